// Round 3
// baseline (796.091 us; speedup 1.0000x reference)
//
#include <hip/hip_runtime.h>
#include <stdint.h>

typedef unsigned short u16;
typedef unsigned int   u32;
typedef short bf16x8 __attribute__((ext_vector_type(8)));
typedef float f32x4  __attribute__((ext_vector_type(4)));

#define N_    64
#define CIN_  64
#define T_    256
#define V_    25
#define COUT_ 128
#define CI_   64
#define EPS_  1e-5f
#define CNT_  409600.0f

#define MFMA16(a,b,c) __builtin_amdgcn_mfma_f32_16x16x32_bf16((a),(b),(c),0,0,0)

__device__ __forceinline__ u16 f2bf(float f) {
  u32 u = __float_as_uint(f);
  u += 0x7fffu + ((u >> 16) & 1u);   // RNE
  return (u16)(u >> 16);
}
__device__ __forceinline__ float bf2f(u16 h) { return __uint_as_float(((u32)h) << 16); }

// ---------------- K0: pack weights to bf16 (W5 = [Wp s0;Wp s1;Wp s2;Wm4;dW], BsT padded) ----
__global__ __launch_bounds__(256) void k_pack(const float* __restrict__ Wp, const float* __restrict__ Wm4,
                                              const float* __restrict__ dW, const float* __restrict__ A,
                                              const float* __restrict__ Al,
                                              u16* __restrict__ w5, u16* __restrict__ bst) {
  int tid0 = blockIdx.x * 256 + threadIdx.x, stride = gridDim.x * 256;
  for (int i = tid0; i < 640 * 64; i += stride) {
    int r = i >> 6, k = i & 63;
    float v = (r < 384) ? Wp[i] : (r < 512) ? Wm4[(r - 384) * 64 + k] : dW[(r - 512) * 64 + k];
    w5[i] = f2bf(v);
  }
  for (int i = tid0; i < 3 * 32 * 32; i += stride) {
    int s = i >> 10, rem = i & 1023, u = rem >> 5, v = rem & 31;
    float val = (u < 25 && v < 25) ? (A[(s * 25 + u) * 25 + v] + Al[(s * 25 + u) * 25 + v]) : 0.f;
    bst[i] = f2bf(val);
  }
}

// ---------------- K1: temporal means of x (forward / backward windows) ----------------
__global__ __launch_bounds__(256) void k_means(const float* __restrict__ x,
                                               float* __restrict__ mf, float* __restrict__ mb) {
  int i = blockIdx.x, n = blockIdx.y;
  const float* src = x + ((size_t)n * CIN_ + i) * T_ * V_;
  __shared__ float xs[T_ * V_];
  __shared__ float pf[8][32], pb[8][32];
  for (int idx = threadIdx.x; idx < T_ * V_; idx += 256) xs[idx] = src[idx];
  __syncthreads();
  int v = threadIdx.x & 31, g = threadIdx.x >> 5;
  float sf = 0.f, sb = 0.f;
  if (v < V_) {
    for (int t = g; t < T_; t += 8) {
      float val = xs[t * V_ + v];
      if (t < T_ - 2) sf += val;
      if (t >= 2)     sb += val;
    }
  }
  pf[g][v] = sf; pb[g][v] = sb;
  __syncthreads();
  if (threadIdx.x < V_) {
    float af = 0.f, ab = 0.f;
    for (int gg = 0; gg < 8; gg++) { af += pf[gg][threadIdx.x]; ab += pb[gg][threadIdx.x]; }
    size_t o = ((size_t)n * CIN_ + i) * V_ + threadIdx.x;
    mf[o] = af * (1.0f / 254.0f);
    mb[o] = ab * (1.0f / 254.0f);
  }
}

// ---------------- K2: Rd' = alpha*tanh(P - Q + bm3) (bf16, v-padded-32) + bias[n][c][u] ----------------
__global__ __launch_bounds__(256) void k_rd(
    const float* __restrict__ mf, const float* __restrict__ mb,
    const float* __restrict__ Wm1, const float* __restrict__ bm1,
    const float* __restrict__ Wm2, const float* __restrict__ bm2,
    const float* __restrict__ Wm3, const float* __restrict__ bm3,
    const float* __restrict__ bm4, const float* __restrict__ alpha,
    const float* __restrict__ A, const float* __restrict__ Al, const float* __restrict__ bp,
    u16* __restrict__ rdws, float* __restrict__ biasws) {
  int n = blockIdx.x;
  int tid = threadIdx.x;
  __shared__ float MfL[CIN_][V_], MbL[CIN_][V_], xfL[CI_][V_], xbL[CI_][V_];
  __shared__ float PL[COUT_ * V_], QL[COUT_ * V_], rsumL[3][V_];
  for (int idx = tid; idx < CIN_ * V_; idx += 256) {
    MfL[idx / V_][idx % V_] = mf[(size_t)n * CIN_ * V_ + idx];
    MbL[idx / V_][idx % V_] = mb[(size_t)n * CIN_ * V_ + idx];
  }
  if (tid < 75) {
    int s = tid / 25, u = tid % 25;
    float acc = 0.f;
    for (int v = 0; v < 25; v++) acc += A[(s * 25 + u) * 25 + v] + Al[(s * 25 + u) * 25 + v];
    rsumL[s][u] = acc;
  }
  __syncthreads();
  for (int idx = tid; idx < CI_ * V_; idx += 256) {
    int o = idx / V_, v = idx % V_;
    float af = bm1[o], ab = bm2[o];
    for (int i = 0; i < CIN_; i++) {
      af += Wm1[o * CIN_ + i] * MfL[i][v];
      ab += Wm2[o * CIN_ + i] * MbL[i][v];
    }
    xfL[o][v] = af; xbL[o][v] = ab;
  }
  __syncthreads();
  for (int idx = tid; idx < COUT_ * V_; idx += 256) {
    int c = idx / V_, u = idx % V_;
    float p = 0.f, q = 0.f;
    for (int i = 0; i < CI_; i++) {
      p += Wm3[c * CI_ + i] * xbL[i][u];
      q += Wm3[c * CI_ + i] * xfL[i][u];
    }
    PL[idx] = p; QL[idx] = q;
  }
  __syncthreads();
  float al = alpha[0];
  for (int r = tid; r < COUT_ * V_; r += 256) {
    int c = r / V_, u = r % V_;
    float pv = PL[r] + bm3[c];
    float acc = 0.f;
    u16* dst = rdws + ((size_t)(n * COUT_ + c) * 25 + u) * 32;
    for (int w = 0; w < 25; w++) {
      float val = al * tanhf(pv - QL[c * V_ + w]);
      dst[w] = f2bf(val);
      acc += val;
    }
    for (int w = 25; w < 32; w++) dst[w] = 0;
    float yb = 0.f;
    for (int s = 0; s < 3; s++) yb += bp[s * COUT_ + c] * rsumL[s][u];
    biasws[(size_t)(n * COUT_ + c) * 25 + u] = bm4[c] * acc + yb;
  }
}

// ---------------- K3: fused MFMA main pass ----------------
// Stage A: [640x64]@[64 x 400pos] bf16 MFMA, per 16-channel group; Xp slabs -> LDS, d slab -> dL LDS.
// Stage B: per (n,c): y[16t x 25u] = Xp[16t x 128kk] @ [BsT(3x32) ; Rd_c(32)], K=128.
// Epilogue: pack (y,d) bf16 into ONE u32 coalesced store + per-channel stats.
__global__ __launch_bounds__(256, 3) void k_main(
    const float* __restrict__ x, const u16* __restrict__ w5, const u16* __restrict__ bst,
    const u16* __restrict__ rdws, const float* __restrict__ biasws,
    u32* __restrict__ out32, float* __restrict__ partials) {
  // union region: staging half-tile (400 x 36 u16 = 28800 B)  /  XpL (16c x 16t x 72 u16 = 36864 B)
  __shared__ __align__(16) char smem[36864];
  __shared__ u16 dls[16 * 425];      // d slab: [cloc][t][v], channel stride 425 (13600 B)
  __shared__ float statsL[512];
  const int tid = threadIdx.x;
  const int w = tid >> 6, l = tid & 63;
  const int lc = l & 15, lq = l >> 4;
  const int n = blockIdx.y, tc = blockIdx.x, t0 = tc * 16;

  // phase 0: stage x in two 32-k halves; frags to registers
  bf16x8 xf[7][2] = {};
  const float* xb = x + (size_t)n * CIN_ * T_ * V_ + (size_t)t0 * V_;
  #pragma unroll
  for (int hf = 0; hf < 2; hf++) {
    u32* xslw = (u32*)smem;
    for (int idx = tid; idx < 16 * 400; idx += 256) {
      int i2 = idx / 400, p = idx - i2 * 400;
      float a = xb[(size_t)(hf * 32 + 2 * i2)     * (T_ * V_) + p];
      float b = xb[(size_t)(hf * 32 + 2 * i2 + 1) * (T_ * V_) + p];
      xslw[p * 18 + i2] = ((u32)f2bf(b) << 16) | (u32)f2bf(a);
    }
    __syncthreads();
    #pragma unroll
    for (int pi = 0; pi < 7; pi++) {
      int pt = w + pi * 4;
      if (pt < 25)
        xf[pi][hf] = *(const bf16x8*)((const u16*)smem + (pt * 16 + lc) * 36 + lq * 8);
    }
    __syncthreads();
  }
  // BsT B-frags (shared by all groups)
  bf16x8 bw[3][2];
  #pragma unroll
  for (int s = 0; s < 3; s++)
    #pragma unroll
    for (int ut = 0; ut < 2; ut++)
      bw[s][ut] = *(const bf16x8*)(bst + (s * 32 + ut * 16 + lc) * 32 + lq * 8);

  // zero XpL pads + statsL
  {
    uint4 z4 = {0, 0, 0, 0};
    uint4* q = (uint4*)smem;
    for (int idx = tid; idx < 2304; idx += 256) q[idx] = z4;
    statsL[tid] = 0.f; statsL[tid + 256] = 0.f;
  }
  __syncthreads();

  u16* xpl = (u16*)smem;   // [c16][t16][72]: slot0 32 + slot1 32 + pad 8
  const f32x4 zz = {0.f, 0.f, 0.f, 0.f};

  for (int g = 0; g < 8; g++) {
    const int c0 = g * 16;
    f32x4 acc[4][2];
    #pragma unroll
    for (int cl = 0; cl < 4; cl++) { acc[cl][0] = zz; acc[cl][1] = zz; }

    #pragma unroll
    for (int h = 0; h < 2; h++) {
      const int nsl = h ? 3 : 2;
      // ---- stage A ----
      bf16x8 af[3][2];
      #pragma unroll
      for (int si = 0; si < 3; si++) if (si < nsl) {
        int sl = h * 2 + si;
        #pragma unroll
        for (int ks = 0; ks < 2; ks++)
          af[si][ks] = *(const bf16x8*)(w5 + ((sl * 128 + c0 + lc) * 64 + ks * 32 + lq * 8));
      }
      #pragma unroll
      for (int pi = 0; pi < 7; pi++) {
        int pt = w + pi * 4;
        if (pt >= 25) continue;
        f32x4 pa[3];
        #pragma unroll
        for (int si = 0; si < 3; si++) if (si < nsl) {
          pa[si] = MFMA16(af[si][0], xf[pi][0], zz);
          pa[si] = MFMA16(af[si][1], xf[pi][1], pa[si]);
        }
        u32 up = (u32)(pt * 16 + lc), t = up / 25u, v = up - t * 25u;
        #pragma unroll
        for (int si = 0; si < 3; si++) if (si < nsl) {
          int sl = h * 2 + si;
          if (sl < 4) {
            int slot = sl & 1;
            u16* dst = xpl + (4 * lq) * 1152 + t * 72 + slot * 32 + v;
            #pragma unroll
            for (int r = 0; r < 4; r++) dst[r * 1152] = f2bf(pa[si][r]);
          } else {   // d slab -> LDS
            u16* dst = dls + (4 * lq) * 425 + t * 26 + v;
            #pragma unroll
            for (int r = 0; r < 4; r++) dst[r * 425] = f2bf(pa[si][r]);
          }
        }
      }
      __syncthreads();

      // ---- stage B: ksteps h*2, h*2+1 (wave owns 4 consecutive channels) ----
      bf16x8 rdf0[4], rdf1[4];
      if (h == 1) {
        #pragma unroll
        for (int cl = 0; cl < 4; cl++) {
          size_t rb = (size_t)(n * COUT_ + c0 + w * 4 + cl) * 25;
          rdf0[cl] = *(const bf16x8*)(rdws + (rb + lc) * 32 + lq * 8);
          int u1c = (lc + 16 < 25) ? lc + 16 : 24;
          rdf1[cl] = *(const bf16x8*)(rdws + (rb + u1c) * 32 + lq * 8);
        }
      }
      #pragma unroll
      for (int cl = 0; cl < 4; cl++) {
        int clocal = w * 4 + cl;
        #pragma unroll
        for (int kl = 0; kl < 2; kl++) {
          bf16x8 aX = *(const bf16x8*)(xpl + clocal * 1152 + lc * 72 + kl * 32 + lq * 8);
          int kk = h * 2 + kl;
          bf16x8 b0, b1;
          if (kk < 3) { b0 = bw[kk][0]; b1 = bw[kk][1]; }
          else        { b0 = rdf0[cl];  b1 = rdf1[cl]; }
          acc[cl][0] = MFMA16(aX, b0, acc[cl][0]);
          acc[cl][1] = MFMA16(aX, b1, acc[cl][1]);
        }
      }
      if (h == 1) {  // epilogue: bias, pack (y,d), store u32, stats
        #pragma unroll
        for (int cl = 0; cl < 4; cl++) {
          int cloc = w * 4 + cl, c = c0 + cloc;
          size_t bb = (size_t)(n * COUT_ + c) * 25;
          float bias0 = biasws[bb + lc];
          int u1 = lc + 16; bool v1 = u1 < 25;
          float bias1 = biasws[bb + (v1 ? u1 : 24)];
          size_t ob = ((size_t)(n * COUT_ + c) * T_ + t0) * V_;
          float sy = 0.f, sq = 0.f, sd = 0.f, sdq = 0.f;
          #pragma unroll
          for (int r = 0; r < 4; r++) {
            int t = 4 * lq + r;
            float y0 = acc[cl][0][r] + bias0;
            float d0 = bf2f(dls[cloc * 425 + t * 26 + lc]);
            out32[ob + t * 25 + lc] = ((u32)f2bf(d0) << 16) | (u32)f2bf(y0);
            sy += y0; sq += y0 * y0; sd += d0; sdq += d0 * d0;
            if (v1) {
              float y1 = acc[cl][1][r] + bias1;
              float d1 = bf2f(dls[cloc * 425 + t * 26 + u1]);
              out32[ob + t * 25 + u1] = ((u32)f2bf(d1) << 16) | (u32)f2bf(y1);
              sy += y1; sq += y1 * y1; sd += d1; sdq += d1 * d1;
            }
          }
          #pragma unroll
          for (int off = 1; off < 64; off <<= 1) {
            sy += __shfl_xor(sy, off); sq += __shfl_xor(sq, off);
            sd += __shfl_xor(sd, off); sdq += __shfl_xor(sdq, off);
          }
          if (l == 0) {
            atomicAdd(&statsL[c * 4 + 0], sy);  atomicAdd(&statsL[c * 4 + 1], sq);
            atomicAdd(&statsL[c * 4 + 2], sd);  atomicAdd(&statsL[c * 4 + 3], sdq);
          }
        }
      }
      __syncthreads();
    }
  }
  int bflat = blockIdx.y * 16 + blockIdx.x;
  for (int j = tid; j < 512; j += 256) partials[(size_t)j * 1024 + bflat] = statsL[j];
}

// ---------------- K4a: reduce partials [512][1024] -> colsum[512], one column per block ----------------
__global__ __launch_bounds__(256) void k_stats1(const float* __restrict__ partials, float* __restrict__ colsum) {
  __shared__ float red[4];
  int j = blockIdx.x, tid = threadIdx.x;
  float s = 0.f;
  #pragma unroll
  for (int i = 0; i < 4; i++) s += partials[(size_t)j * 1024 + i * 256 + tid];
  #pragma unroll
  for (int off = 1; off < 64; off <<= 1) s += __shfl_xor(s, off);
  if ((tid & 63) == 0) red[tid >> 6] = s;
  __syncthreads();
  if (tid == 0) colsum[j] = red[0] + red[1] + red[2] + red[3];
}

// ---------------- K4b: BN affine params ----------------
__global__ __launch_bounds__(128) void k_stats2(
    const float* __restrict__ colsum,
    const float* __restrict__ bn_g, const float* __restrict__ bn_b,
    const float* __restrict__ dn_g, const float* __restrict__ dn_b,
    float* __restrict__ params) {
  int c = threadIdx.x;
  float sy = colsum[c * 4], syy = colsum[c * 4 + 1], sd = colsum[c * 4 + 2], sdd = colsum[c * 4 + 3];
  float muY = sy / CNT_, varY = syy / CNT_ - muY * muY;
  float muD = sd / CNT_, varD = sdd / CNT_ - muD * muD;
  float sY = bn_g[c] * rsqrtf(varY + EPS_);
  float sD = dn_g[c] * rsqrtf(varD + EPS_);
  float off = bn_b[c] - muY * sY + dn_b[c] - muD * sD;
  params[c * 4 + 0] = sY; params[c * 4 + 1] = sD; params[c * 4 + 2] = off;
}

// ---------------- K5: in-place finalize: relu(y*sY + d*sD + off), uint4 ----------------
__global__ __launch_bounds__(256) void k_final(uint4* __restrict__ io, const float* __restrict__ params) {
  int slab = blockIdx.x;             // n*COUT_ + c
  int c = slab & (COUT_ - 1);
  float sY = params[c * 4], sD = params[c * 4 + 1], off = params[c * 4 + 2];
  size_t base = (size_t)slab * 1600;   // 6400 u32 = 1600 uint4 per slab
  #pragma unroll
  for (int j = 0; j < 7; j++) {
    int idx = j * 256 + threadIdx.x;
    if (idx < 1600) {
      uint4 wv = io[base + idx];
      u32 ws[4] = {wv.x, wv.y, wv.z, wv.w};
      #pragma unroll
      for (int e = 0; e < 4; e++) {
        float y = bf2f((u16)(ws[e] & 0xffffu));
        float d = bf2f((u16)(ws[e] >> 16));
        float val = fmaf(y, sY, fmaf(d, sD, off));
        ws[e] = __float_as_uint(fmaxf(val, 0.0f));
      }
      io[base + idx] = make_uint4(ws[0], ws[1], ws[2], ws[3]);
    }
  }
}

extern "C" void kernel_launch(void* const* d_in, const int* in_sizes, int n_in,
                              void* d_out, int out_size, void* d_ws, size_t ws_size,
                              hipStream_t stream) {
  const float* x    = (const float*)d_in[0];
  const float* A    = (const float*)d_in[1];
  const float* Al   = (const float*)d_in[2];
  const float* Wp   = (const float*)d_in[3];
  const float* bp   = (const float*)d_in[4];
  const float* Wm1  = (const float*)d_in[5];
  const float* bm1  = (const float*)d_in[6];
  const float* Wm2  = (const float*)d_in[7];
  const float* bm2  = (const float*)d_in[8];
  const float* Wm3  = (const float*)d_in[9];
  const float* bm3  = (const float*)d_in[10];
  const float* Wm4  = (const float*)d_in[11];
  const float* bm4  = (const float*)d_in[12];
  const float* alpha= (const float*)d_in[13];
  const float* bn_g = (const float*)d_in[14];
  const float* bn_b = (const float*)d_in[15];
  const float* dW   = (const float*)d_in[16];
  const float* dn_g = (const float*)d_in[17];
  const float* dn_b = (const float*)d_in[18];

  // workspace layout (bytes, 16B-aligned), total ~16.9 MB
  char* ws = (char*)d_ws;
  float* mf       = (float*)(ws + 0);              //   409,600
  float* mb       = (float*)(ws + 409600);         //   409,600
  u16*   rdws     = (u16*)  (ws + 819200);         // 13,107,200  [n][128][25][32] bf16
  float* biasws   = (float*)(ws + 13926400);       //   819,200   [n][128][25]
  u16*   w5       = (u16*)  (ws + 14745600);       //    81,920   [640][64] bf16
  u16*   bstw     = (u16*)  (ws + 14827520);       //     6,144   [3][32][32] bf16
  float* partials = (float*)(ws + 14833664);       // 2,097,152   [512][1024]
  float* colsum   = (float*)(ws + 16930816);       //     2,048
  float* params   = (float*)(ws + 16932864);       //     2,048

  k_pack <<<dim3(41),      dim3(256), 0, stream>>>(Wp, Wm4, dW, A, Al, w5, bstw);
  k_means<<<dim3(64, 64),  dim3(256), 0, stream>>>(x, mf, mb);
  k_rd   <<<dim3(64),      dim3(256), 0, stream>>>(mf, mb, Wm1, bm1, Wm2, bm2, Wm3, bm3,
                                                   bm4, alpha, A, Al, bp, rdws, biasws);
  k_main <<<dim3(16, 64),  dim3(256), 0, stream>>>(x, w5, bstw, rdws, biasws,
                                                   (u32*)d_out, partials);
  k_stats1<<<dim3(512),    dim3(256), 0, stream>>>(partials, colsum);
  k_stats2<<<dim3(1),      dim3(128), 0, stream>>>(colsum, bn_g, bn_b, dn_g, dn_b, params);
  k_final<<<dim3(64 * 128),dim3(256), 0, stream>>>((uint4*)d_out, params);
}